// Round 3
// baseline (104.704 us; speedup 1.0000x reference)
//
#include <hip/hip_runtime.h>

#define NROWS 2097152
#define EPSV 0.001f

// One thread handles rows 4t..4t+3: 6 float4 loads (96 B/thread, all bytes
// used -> exact HBM traffic) + 2 float4 stores. vs the 2-row version this
// doubles per-thread memory-level parallelism (6 outstanding 16B loads
// before the dependent ALU chain) and makes the grid an exact 2048 blocks
// (8 blocks/CU, no tail check). HBM floor ~10.2 us at 6.3 TB/s.
// [Rounds 0-2: MI355X container infra failures; no counters produced. This
// is the round-0 candidate resubmitted unchanged — it is still the live,
// unmeasured experiment. Do not stack unmeasured mutations.]
__global__ __launch_bounds__(256) void delan_tau_kernel(
    const float* __restrict__ x,
    const float* __restrict__ W1, const float* __restrict__ b1,
    const float* __restrict__ W2, const float* __restrict__ b2,
    const float* __restrict__ W3, const float* __restrict__ b3,
    const float* __restrict__ W4, const float* __restrict__ b4,
    float* __restrict__ out)
{
    const int t = blockIdx.x * blockDim.x + threadIdx.x; // rows 4t..4t+3
    // NROWS/4 = 524288 threads = 2048 blocks * 256 exactly: no bounds check.

    // ---- issue all 6 input float4 loads up front (max loads in flight) ----
    const float4* x4 = reinterpret_cast<const float4*>(x) + 6u * (unsigned)t;
    const float4 v0 = x4[0];
    const float4 v1 = x4[1];
    const float4 v2 = x4[2];
    const float4 v3 = x4[3];
    const float4 v4 = x4[4];
    const float4 v5 = x4[5];

    // ---- uniform weight loads (scalar-cached; issue after the vector loads) ----
    float w1[12], bb1[6], w2[12], bb2[2], w3[12], bb3[2], w4[6];
    #pragma unroll
    for (int i = 0; i < 12; ++i) w1[i] = W1[i];
    #pragma unroll
    for (int i = 0; i < 6; ++i)  bb1[i] = b1[i];
    #pragma unroll
    for (int i = 0; i < 12; ++i) w2[i] = W2[i];
    bb2[0] = b2[0]; bb2[1] = b2[1];
    #pragma unroll
    for (int i = 0; i < 12; ++i) w3[i] = W3[i];
    bb3[0] = b3[0]; bb3[1] = b3[1];
    #pragma unroll
    for (int i = 0; i < 6; ++i)  w4[i] = W4[i];
    const float bb4 = b4[0];

    const float rows[4][6] = {
        { v0.x, v0.y, v0.z, v0.w, v1.x, v1.y },
        { v1.z, v1.w, v2.x, v2.y, v2.z, v2.w },
        { v3.x, v3.y, v3.z, v3.w, v4.x, v4.y },
        { v4.z, v4.w, v5.x, v5.y, v5.z, v5.w }
    };

    float res[8];

    #pragma unroll
    for (int rr = 0; rr < 4; ++rr) {
        const float q0 = rows[rr][0], q1 = rows[rr][1];
        const float qd0 = rows[rr][2], qd1 = rows[rr][3];
        const float qdd0 = rows[rr][4], qdd1 = rows[rr][5];

        // layer 1: h = relu(W1 q + b1), m = mask
        float h[6], m[6];
        #pragma unroll
        for (int j = 0; j < 6; ++j) {
            const float pre = fmaf(w1[2 * j], q0, fmaf(w1[2 * j + 1], q1, bb1[j]));
            const bool pos = pre > 0.0f;
            h[j] = pos ? pre : 0.0f;
            m[j] = pos ? 1.0f : 0.0f;
        }

        // heads: g (2), ld_pre (2), lo (1)
        float g0 = bb2[0], g1 = bb2[1], ldp0 = bb3[0], ldp1 = bb3[1], lo = bb4;
        #pragma unroll
        for (int j = 0; j < 6; ++j) {
            g0   = fmaf(h[j], w2[j],     g0);
            g1   = fmaf(h[j], w2[6 + j], g1);
            ldp0 = fmaf(h[j], w3[j],     ldp0);
            ldp1 = fmaf(h[j], w3[6 + j], ldp1);
            lo   = fmaf(h[j], w4[j],     lo);
        }
        const float p = ldp0 > 0.0f ? ldp0 : 0.0f;   // L00
        const float s = ldp1 > 0.0f ? ldp1 : 0.0f;   // L11
        const float md0 = ldp0 > 0.0f ? 1.0f : 0.0f;
        const float md1 = ldp1 > 0.0f ? 1.0f : 0.0f;
        const float r = lo;                           // L10

        // Jacobians: dld_dq[i][k] = md_i * sum_j W3[i][j]*m[j]*W1[j][k];
        //            dlo_dq[k]   = sum_j W4[j]*m[j]*W1[j][k]
        float s00 = 0.f, s01 = 0.f, s10 = 0.f, s11 = 0.f, c0 = 0.f, c1 = 0.f;
        #pragma unroll
        for (int j = 0; j < 6; ++j) {
            const float d0 = m[j] * w1[2 * j];
            const float d1 = m[j] * w1[2 * j + 1];
            s00 = fmaf(w3[j],     d0, s00);
            s01 = fmaf(w3[j],     d1, s01);
            s10 = fmaf(w3[6 + j], d0, s10);
            s11 = fmaf(w3[6 + j], d1, s11);
            c0  = fmaf(w4[j],     d0, c0);
            c1  = fmaf(w4[j],     d1, c1);
        }
        const float dq00 = md0 * s00, dq01 = md0 * s01;
        const float dq10 = md1 * s10, dq11 = md1 * s11;

        // time derivatives
        const float a = fmaf(dq00, qd0, dq01 * qd1); // dld_dt[0]
        const float b = fmaf(dq10, qd0, dq11 * qd1); // dld_dt[1]
        const float c = fmaf(c0,   qd0, c1   * qd1); // dlo_dt

        // H = L^T L + eps I  (L = [[p,0],[r,s]])
        const float H00 = fmaf(p, p, fmaf(r, r, EPSV));
        const float H01 = r * s;
        const float H11 = fmaf(s, s, EPSV);

        // dH_dt
        const float dH00 = 2.0f * a * p;
        const float dH01 = fmaf(p, c, a * r);
        const float dH11 = 2.0f * fmaf(r, c, s * b);

        // quadratic velocity term
        const float k00 = qd0 * qd0, k01 = qd0 * qd1, k11 = qd1 * qd1;
        const float quad0 = 2.0f * (dq00 * p * k00 + fmaf(p, c0, dq00 * r) * k01
                                    + fmaf(r, c0, s * dq10) * k11);
        const float quad1 = 2.0f * (dq01 * p * k00 + fmaf(p, c1, dq01 * r) * k01
                                    + fmaf(r, c1, s * dq11) * k11);

        const float tau0 = fmaf(H00, qdd0, fmaf(H01, qdd1,
                           fmaf(dH00, qd0, fmaf(dH01, qd1, quad0 + g0))));
        const float tau1 = fmaf(H01, qdd0, fmaf(H11, qdd1,
                           fmaf(dH01, qd0, fmaf(dH11, qd1, quad1 + g1))));
        res[2 * rr + 0] = tau0;
        res[2 * rr + 1] = tau1;
    }

    // ---- coalesced float4 stores: out rows 4t..4t+3 = float4 indices 2t,2t+1 ----
    float4* o4 = reinterpret_cast<float4*>(out) + 2u * (unsigned)t;
    o4[0] = make_float4(res[0], res[1], res[2], res[3]);
    o4[1] = make_float4(res[4], res[5], res[6], res[7]);
}

extern "C" void kernel_launch(void* const* d_in, const int* in_sizes, int n_in,
                              void* d_out, int out_size, void* d_ws, size_t ws_size,
                              hipStream_t stream) {
    const float* x  = (const float*)d_in[0];
    const float* W1 = (const float*)d_in[1];
    const float* b1 = (const float*)d_in[2];
    const float* W2 = (const float*)d_in[3];
    const float* b2 = (const float*)d_in[4];
    const float* W3 = (const float*)d_in[5];
    const float* b3 = (const float*)d_in[6];
    const float* W4 = (const float*)d_in[7];
    const float* b4 = (const float*)d_in[8];
    float* out = (float*)d_out;

    const int threads = 256;
    const int nthreads_total = NROWS / 4;           // 4 rows per thread
    const int blocks = nthreads_total / threads;    // 2048 exactly
    delan_tau_kernel<<<blocks, threads, 0, stream>>>(x, W1, b1, W2, b2, W3, b3,
                                                     W4, b4, out);
}

// Round 4
// 101.578 us; speedup vs baseline: 1.0308x; 1.0308x over previous
//
#include <hip/hip_runtime.h>

#define NROWS 2097152
#define EPSV 0.001f

// Two rows per thread, LDS-staged coalesced input:
//  - each 256-thread block owns 512 rows = 768 float4 = 12 KiB of x
//  - 3 unit-stride float4 loads per thread (1 KiB contiguous per wave instr,
//    minimal L1 transactions) -> LDS -> each thread reads its 48 B slice
//    (48 B lane stride = 2-way LDS bank aliasing = free per m136)
//  - store: one float4 per thread, unit-stride across lanes (coalesced)
// HBM traffic exact: 48 MiB in + 16 MiB out; floor ~10.2 us at 6.3 TB/s.
// [R3 evidence: kernel dispatch < 41 us (absent from top-5; fills at 42 us
//  dominate the timed window). 4-row variant was neutral/worse (VGPR
//  occupancy step) -> reverted to 2-row. This round's single variable:
//  lane-strided global loads -> unit-stride + LDS stage.]
__global__ __launch_bounds__(256) void delan_tau_kernel(
    const float* __restrict__ x,
    const float* __restrict__ W1, const float* __restrict__ b1,
    const float* __restrict__ W2, const float* __restrict__ b2,
    const float* __restrict__ W3, const float* __restrict__ b3,
    const float* __restrict__ W4, const float* __restrict__ b4,
    float* __restrict__ out)
{
    __shared__ float4 xs[768];                 // 12 KiB
    const int tid = threadIdx.x;
    const unsigned base = (unsigned)blockIdx.x * 768u;   // block's float4 base
    // 4096 blocks * 256 threads * 2 rows = 2097152 rows exactly: no guard.

    // ---- coalesced global loads: unit-stride float4 across lanes ----
    const float4* x4 = reinterpret_cast<const float4*>(x);
    const float4 a0 = x4[base + (unsigned)tid];
    const float4 a1 = x4[base + 256u + (unsigned)tid];
    const float4 a2 = x4[base + 512u + (unsigned)tid];

    // ---- uniform weight loads (scalar-cached; overlap with vmem latency) ----
    float w1[12], bb1[6], w2[12], bb2[2], w3[12], bb3[2], w4[6];
    #pragma unroll
    for (int i = 0; i < 12; ++i) w1[i] = W1[i];
    #pragma unroll
    for (int i = 0; i < 6; ++i)  bb1[i] = b1[i];
    #pragma unroll
    for (int i = 0; i < 12; ++i) w2[i] = W2[i];
    bb2[0] = b2[0]; bb2[1] = b2[1];
    #pragma unroll
    for (int i = 0; i < 12; ++i) w3[i] = W3[i];
    bb3[0] = b3[0]; bb3[1] = b3[1];
    #pragma unroll
    for (int i = 0; i < 6; ++i)  w4[i] = W4[i];
    const float bb4 = b4[0];

    // ---- LDS transpose: block-contiguous -> per-thread-contiguous ----
    xs[tid]        = a0;
    xs[256 + tid]  = a1;
    xs[512 + tid]  = a2;
    __syncthreads();
    const float4 v0 = xs[3 * tid + 0];
    const float4 v1 = xs[3 * tid + 1];
    const float4 v2 = xs[3 * tid + 2];

    const float rows[2][6] = {
        { v0.x, v0.y, v0.z, v0.w, v1.x, v1.y },
        { v1.z, v1.w, v2.x, v2.y, v2.z, v2.w }
    };

    float res[4];

    #pragma unroll
    for (int rr = 0; rr < 2; ++rr) {
        const float q0 = rows[rr][0], q1 = rows[rr][1];
        const float qd0 = rows[rr][2], qd1 = rows[rr][3];
        const float qdd0 = rows[rr][4], qdd1 = rows[rr][5];

        // layer 1: h = relu(W1 q + b1), m = mask
        float h[6], m[6];
        #pragma unroll
        for (int j = 0; j < 6; ++j) {
            const float pre = fmaf(w1[2 * j], q0, fmaf(w1[2 * j + 1], q1, bb1[j]));
            const bool pos = pre > 0.0f;
            h[j] = pos ? pre : 0.0f;
            m[j] = pos ? 1.0f : 0.0f;
        }

        // heads: g (2), ld_pre (2), lo (1)
        float g0 = bb2[0], g1 = bb2[1], ldp0 = bb3[0], ldp1 = bb3[1], lo = bb4;
        #pragma unroll
        for (int j = 0; j < 6; ++j) {
            g0   = fmaf(h[j], w2[j],     g0);
            g1   = fmaf(h[j], w2[6 + j], g1);
            ldp0 = fmaf(h[j], w3[j],     ldp0);
            ldp1 = fmaf(h[j], w3[6 + j], ldp1);
            lo   = fmaf(h[j], w4[j],     lo);
        }
        const float p = ldp0 > 0.0f ? ldp0 : 0.0f;   // L00
        const float s = ldp1 > 0.0f ? ldp1 : 0.0f;   // L11
        const float md0 = ldp0 > 0.0f ? 1.0f : 0.0f;
        const float md1 = ldp1 > 0.0f ? 1.0f : 0.0f;
        const float r = lo;                           // L10

        // Jacobians: dld_dq[i][k] = md_i * sum_j W3[i][j]*m[j]*W1[j][k];
        //            dlo_dq[k]   = sum_j W4[j]*m[j]*W1[j][k]
        float s00 = 0.f, s01 = 0.f, s10 = 0.f, s11 = 0.f, c0 = 0.f, c1 = 0.f;
        #pragma unroll
        for (int j = 0; j < 6; ++j) {
            const float d0 = m[j] * w1[2 * j];
            const float d1 = m[j] * w1[2 * j + 1];
            s00 = fmaf(w3[j],     d0, s00);
            s01 = fmaf(w3[j],     d1, s01);
            s10 = fmaf(w3[6 + j], d0, s10);
            s11 = fmaf(w3[6 + j], d1, s11);
            c0  = fmaf(w4[j],     d0, c0);
            c1  = fmaf(w4[j],     d1, c1);
        }
        const float dq00 = md0 * s00, dq01 = md0 * s01;
        const float dq10 = md1 * s10, dq11 = md1 * s11;

        // time derivatives
        const float a = fmaf(dq00, qd0, dq01 * qd1); // dld_dt[0]
        const float b = fmaf(dq10, qd0, dq11 * qd1); // dld_dt[1]
        const float c = fmaf(c0,   qd0, c1   * qd1); // dlo_dt

        // H = L^T L + eps I  (L = [[p,0],[r,s]])
        const float H00 = fmaf(p, p, fmaf(r, r, EPSV));
        const float H01 = r * s;
        const float H11 = fmaf(s, s, EPSV);

        // dH_dt
        const float dH00 = 2.0f * a * p;
        const float dH01 = fmaf(p, c, a * r);
        const float dH11 = 2.0f * fmaf(r, c, s * b);

        // quadratic velocity term
        const float k00 = qd0 * qd0, k01 = qd0 * qd1, k11 = qd1 * qd1;
        const float quad0 = 2.0f * (dq00 * p * k00 + fmaf(p, c0, dq00 * r) * k01
                                    + fmaf(r, c0, s * dq10) * k11);
        const float quad1 = 2.0f * (dq01 * p * k00 + fmaf(p, c1, dq01 * r) * k01
                                    + fmaf(r, c1, s * dq11) * k11);

        const float tau0 = fmaf(H00, qdd0, fmaf(H01, qdd1,
                           fmaf(dH00, qd0, fmaf(dH01, qd1, quad0 + g0))));
        const float tau1 = fmaf(H01, qdd0, fmaf(H11, qdd1,
                           fmaf(dH01, qd0, fmaf(dH11, qd1, quad1 + g1))));
        res[2 * rr + 0] = tau0;
        res[2 * rr + 1] = tau1;
    }

    // ---- coalesced float4 store: out rows for thread t at float4 index
    //      blockIdx.x*256 + tid -> unit-stride across lanes ----
    reinterpret_cast<float4*>(out)[(unsigned)blockIdx.x * 256u + (unsigned)tid] =
        make_float4(res[0], res[1], res[2], res[3]);
}

extern "C" void kernel_launch(void* const* d_in, const int* in_sizes, int n_in,
                              void* d_out, int out_size, void* d_ws, size_t ws_size,
                              hipStream_t stream) {
    const float* x  = (const float*)d_in[0];
    const float* W1 = (const float*)d_in[1];
    const float* b1 = (const float*)d_in[2];
    const float* W2 = (const float*)d_in[3];
    const float* b2 = (const float*)d_in[4];
    const float* W3 = (const float*)d_in[5];
    const float* b3 = (const float*)d_in[6];
    const float* W4 = (const float*)d_in[7];
    const float* b4 = (const float*)d_in[8];
    float* out = (float*)d_out;

    const int threads = 256;
    const int nthreads_total = NROWS / 2;           // 2 rows per thread
    const int blocks = nthreads_total / threads;    // 4096 exactly
    delan_tau_kernel<<<blocks, threads, 0, stream>>>(x, W1, b1, W2, b2, W3, b3,
                                                     W4, b4, out);
}